// Round 2
// baseline (110.799 us; speedup 1.0000x reference)
//
#include <hip/hip_runtime.h>
#include <stdint.h>

// GPTQ 4-bit fused dequant-GEMM, MI355X gfx950.  Round 8.
// M=128, K=4096, N=11008, group=128, g_idx[k]=k>>7 (affine).
//
// R7 (f16 partials + packed szp) = 105.0 us; top-5 all harness 256MiB 0xAA
// ws-fills (~85us fixed across the measurement) -> controllable ~19us.
// R8 deletes the split-K partial round-trip:
//  * k_prep now also writes out = bias (5.6 MB).
//  * k_gemm epilogue: pair-merged f32 accs go straight to out via
//    unsafeAtomicAdd (native global_atomic_add_f32, device-scope).  16
//    consecutive lanes hit 64B-contiguous addresses -> coalesced bursts.
//    Removes 11.3 MB part write + 11.3 MB part read + 5.6 MB out write and
//    the f16-partial rounding term (f32 end-to-end accumulation now).
//  * k_reduce deleted -> one fewer kernel + launch gap.
//  * szp packed to 4B {s, -(z+1)s}; S2={s,s/16} rebuilt with one exact
//    pow2 f16 mul (bit-identical to R7's table value).
// Unchanged: exact-cancellation f16 magic dequant (precision guard), XOR-
// swizzled async global_load_lds A-dbuf, 64m x 32n wave tile, kk-split wave
// pairs with LDS pair-reduction, split-K x4 grid (172,4).

#define M_DIM 128
#define K_DIM 4096
#define N_DIM 11008
#define GS    128
#define NG    32
#define SPLIT 4
#define GPB   (NG / SPLIT)           // 8 groups per block
#define NB    (N_DIM / 64)           // 172 n-blocks

typedef _Float16 half8  __attribute__((ext_vector_type(8)));
typedef _Float16 half2t __attribute__((ext_vector_type(2)));
typedef _Float16 half4t __attribute__((ext_vector_type(4)));
typedef float    f32x4  __attribute__((ext_vector_type(4)));

// ---------------- prep ------------------------------------------------------
// blocks [0,512):    x f32 -> xh f16                (512*256*4 == 524288)
// blocks [512,1888): szp packed {s, -(z+1)s} f16x2  (32 g x 43 nb x 256)
// blocks [1888,3264): out = bias                    (1376*256*4 == 1409024)
__global__ void k_prep(const float* __restrict__ x, const int* __restrict__ qzeros,
                       const float* __restrict__ scales, const float* __restrict__ bias,
                       _Float16* __restrict__ xh, _Float16* __restrict__ szp,
                       float* __restrict__ out) {
    int b = blockIdx.x, tid = threadIdx.x;
    if (b < 512) {
        int i = (b * 256 + tid) * 4;
        float4 v = *(const float4*)(x + i);
        half4t o;
        o[0] = (_Float16)v.x; o[1] = (_Float16)v.y;
        o[2] = (_Float16)v.z; o[3] = (_Float16)v.w;
        *(half4t*)(xh + i) = o;
    } else if (b < 1888) {
        b -= 512;
        int g = b / 43;
        int n = (b - g * 43) * 256 + tid;            // 43*256 == 11008 exact
        unsigned qz = (unsigned)qzeros[g * (N_DIM / 8) + (n >> 3)];
        float s  = scales[g * N_DIM + n];
        float z1 = (float)((qz >> ((n & 7) * 4)) & 15u) + 1.0f;
        half2t o;
        o[0] = (_Float16)s;
        o[1] = (_Float16)(-(z1 * s));
        *(half2t*)(szp + (size_t)(g * N_DIM + n) * 2) = o;
    } else {
        int i = ((b - 1888) * 256 + tid) * 4;        // over 128*11008 f32
        int m = i / N_DIM;
        int n = i - m * N_DIM;                       // N_DIM%4==0 -> n%4==0
        *(float4*)(out + i) = *(const float4*)(bias + n);
    }
}

// async 16B/lane global->LDS; lds base wave-uniform, lane i -> base + i*16.
__device__ __forceinline__ void load_lds16(const void* g, void* l) {
    __builtin_amdgcn_global_load_lds(
        (const __attribute__((address_space(1))) unsigned int*)g,
        (__attribute__((address_space(3))) unsigned int*)l, 16, 0, 0);
}

// nibble pair p (nibbles 2p, 2p+1) of q -> two f16 weights:
//  t  = {0x6400|nib_lo, 0x6400|nib_hi<<4} = {1024+q_lo, 1024+16*q_hi}
//  qf = t - 1024                  (EXACT in f16: integers <= 2048)
//  w  = fma(qf, {s, s/16}, {-z1}) where z1 = (z+1)*s
// No pointer casts: pure vector ops, SROA-safe (scratch regression guard).
__device__ __forceinline__ half8 dequant8(unsigned q, half2t S2, half2t Z2) {
    const half2t BIAS = __builtin_bit_cast(half2t, 0x64006400u);
    half2t w[4];
#pragma unroll
    for (int p = 0; p < 4; ++p) {
        unsigned r = __builtin_amdgcn_perm(q, q, 0x00010001u * (unsigned)p); // byte p -> bytes 0,2
        unsigned t = (r & 0x00F0000Fu) | 0x64006400u;                        // v_and_or_b32
        w[p] = __builtin_elementwise_fma(__builtin_bit_cast(half2t, t) - BIAS, S2, Z2);
    }
    half4t lo = __builtin_shufflevector(w[0], w[1], 0, 1, 2, 3);
    half4t hi = __builtin_shufflevector(w[2], w[3], 0, 1, 2, 3);
    return __builtin_shufflevector(lo, hi, 0, 1, 2, 3, 4, 5, 6, 7);
}

// ---------------- main fused kernel ----------------
__global__ __launch_bounds__(512, 4)
void k_gemm(const _Float16* __restrict__ xh,     // [128][4096] f16
            const int*      __restrict__ qweight,// [512][11008] int32
            const _Float16* __restrict__ szp,    // [32][11008] packed {s,-z1}
            float*          __restrict__ out)    // [128][11008], pre-filled bias
{
    // Double-buffered A tile: logical (m,kb) of buffer b at
    //   As[b][m*128 + (kb ^ (m&15))*8]   (halfs)
    // Staged so chunk c = it*512+tid lands at byte offset c*16.
    __shared__ _Float16 As[2][128 * 128];   // 2 x 32 KB

    const int tid  = threadIdx.x;
    const int lane = tid & 63;
    const int w    = tid >> 6;    // 0..7
    const int wx   = w & 1;        // n offset 32*wx
    const int wy   = (w >> 1) & 1; // m offset 64*wy
    const int kh   = w >> 2;       // kk-half: kh=0 -> kk{0,1}, kh=1 -> kk{2,3}
    const int q    = lane >> 4;    // quad
    const int lr   = lane & 15;

    const int n0 = blockIdx.x * 64;
    const int g0 = blockIdx.y * GPB;
    int ncol[2] = { n0 + wx * 32 + lr, n0 + wx * 32 + lr + 16 };

    f32x4 acc[4][2];
#pragma unroll
    for (int f = 0; f < 4; ++f)
#pragma unroll
        for (int h = 0; h < 2; ++h)
            acc[f][h] = (f32x4){0.f, 0.f, 0.f, 0.f};

    // per-lane staging geometry: c = it*512 + tid; m=c>>4; kb=(c&15)^(m&15)
    int cm[4], ckb[4];
#pragma unroll
    for (int it = 0; it < 4; ++it) {
        int c = it * 512 + tid;
        cm[it]  = c >> 4;
        ckb[it] = (c & 15) ^ (cm[it] & 15);
    }
    const int wave_lds = w * 64 * 8;   // halfs

    // ---- prime group g0 ----
#pragma unroll
    for (int it = 0; it < 4; ++it)
        load_lds16(xh + (size_t)cm[it] * K_DIM + g0 * GS + ckb[it] * 8,
                   &As[0][it * 512 * 8 + wave_lds]);
    unsigned qwn[4];
    half2t   szn[2];
#pragma unroll
    for (int t = 0; t < 2; ++t)
#pragma unroll
        for (int h = 0; h < 2; ++h)
            qwn[t * 2 + h] = (unsigned)qweight[(size_t)(g0 * 16 + (kh * 2 + t) * 4 + q) * N_DIM + ncol[h]];
#pragma unroll
    for (int h = 0; h < 2; ++h)
        szn[h] = *(const half2t*)(szp + ((size_t)g0 * N_DIM + ncol[h]) * 2);

    int p = 0;
    for (int g = 0; g < GPB; ++g) {
        unsigned qw[4];
        half2t   sz[2];
#pragma unroll
        for (int i = 0; i < 4; ++i) qw[i] = qwn[i];
#pragma unroll
        for (int h = 0; h < 2; ++h) sz[h] = szn[h];

        __syncthreads();   // A(g) resident in As[p]

        if (g + 1 < GPB) { // next group's async loads in flight under compute
            int gn = g0 + g + 1;
#pragma unroll
            for (int it = 0; it < 4; ++it)
                load_lds16(xh + (size_t)cm[it] * K_DIM + gn * GS + ckb[it] * 8,
                           &As[p ^ 1][it * 512 * 8 + wave_lds]);
#pragma unroll
            for (int t = 0; t < 2; ++t)
#pragma unroll
                for (int h = 0; h < 2; ++h)
                    qwn[t * 2 + h] = (unsigned)qweight[(size_t)(gn * 16 + (kh * 2 + t) * 4 + q) * N_DIM + ncol[h]];
#pragma unroll
            for (int h = 0; h < 2; ++h)
                szn[h] = *(const half2t*)(szp + ((size_t)gn * N_DIM + ncol[h]) * 2);
        }

        half2t S2[2], Z2[2];
#pragma unroll
        for (int h = 0; h < 2; ++h) {
            S2[h][0] = sz[h][0];
            S2[h][1] = sz[h][0] * (_Float16)0.0625f;  // exact pow2 scale
            Z2[h][0] = sz[h][1];
            Z2[h][1] = sz[h][1];
        }

#pragma unroll
        for (int t = 0; t < 2; ++t) {
            const int kk = kh * 2 + t;
            half8 bf[2];
#pragma unroll
            for (int h = 0; h < 2; ++h)
                bf[h] = dequant8(qw[t * 2 + h], S2[h], Z2[h]);
#pragma unroll
            for (int f = 0; f < 4; ++f) {
                int m   = wy * 64 + f * 16 + lr;
                int kb2 = (kk * 4 + q) ^ lr;     // m&15 == lr
                half8 af = *(const half8*)(&As[p][m * 128 + kb2 * 8]);
#pragma unroll
                for (int h = 0; h < 2; ++h)
                    acc[f][h] = __builtin_amdgcn_mfma_f32_16x16x32_f16(af, bf[h], acc[f][h], 0, 0, 0);
            }
        }
        p ^= 1;
    }

    // ---- pair reduction (w, w^4) through LDS, then atomic-add into out ----
    __syncthreads();                       // all A reads done; LDS reusable
    float* red = (float*)&As[0][0];        // 32 KB: 4 pairs x 8 KB
    const int pid = w & 3;
    if (w >= 4) {
#pragma unroll
        for (int f = 0; f < 4; ++f)
#pragma unroll
            for (int h = 0; h < 2; ++h)
                *(f32x4*)(red + pid * 2048 + (f * 2 + h) * 256 + lane * 4) = acc[f][h];
    }
    __syncthreads();
    if (w < 4) {
#pragma unroll
        for (int f = 0; f < 4; ++f) {
            int mrow = wy * 64 + f * 16 + q * 4;
#pragma unroll
            for (int h = 0; h < 2; ++h) {
                f32x4 o = acc[f][h] + *(const f32x4*)(red + pid * 2048 + (f * 2 + h) * 256 + lane * 4);
#pragma unroll
                for (int r = 0; r < 4; ++r)
                    unsafeAtomicAdd(&out[(size_t)(mrow + r) * N_DIM + ncol[h]], o[r]);
            }
        }
    }
}

extern "C" void kernel_launch(void* const* d_in, const int* in_sizes, int n_in,
                              void* d_out, int out_size, void* d_ws, size_t ws_size,
                              hipStream_t stream) {
    const float* x       = (const float*)d_in[0];
    const int*   qweight = (const int*)d_in[1];
    const int*   qzeros  = (const int*)d_in[2];
    const float* scales  = (const float*)d_in[3];
    const float* bias    = (const float*)d_in[4];
    // d_in[5] = g_idx, affine by construction -> unused

    char* ws = (char*)d_ws;
    _Float16* xh  = (_Float16*)ws;                           // 1,048,576 B
    _Float16* szp = (_Float16*)(ws + 1048576);               // 1,409,024 B

    k_prep<<<dim3(3264),       dim3(256), 0, stream>>>(x, qzeros, scales, bias,
                                                       xh, szp, (float*)d_out);
    k_gemm<<<dim3(NB, SPLIT),  dim3(512), 0, stream>>>(xh, qweight, szp, (float*)d_out);
}

// Round 3
// 100.957 us; speedup vs baseline: 1.0975x; 1.0975x over previous
//
#include <hip/hip_runtime.h>
#include <stdint.h>

// GPTQ 4-bit fused dequant-GEMM, MI355X gfx950.  Round 9.
// M=128, K=4096, N=11008, group=128, g_idx[k]=k>>7 (affine).
//
// R8 (per-element f32 atomics for split-K) regressed 105.0 -> 110.8: 5.6M
// device-scope RMWs across non-coherent XCD L2s ~1.6ns each.  Lesson: cross
// the XCD boundary once per block (kernel boundary), never per element.
// R9 = R7 structure (f16 flat partials + k_reduce as the split-K fence)
// with the wave tile reshaped 64m x 32n -> 128m x 16n x 64k:
//  * 8 waves = 4 n-slices x 2 k-halves; wy-pair B duplication eliminated.
//  * dequant8/wave/group 4 -> 2, qweight lane-loads 4 -> 2, szp loads 2 -> 1;
//    B-fragment reuse 4 -> 8 MFMAs per dequant.  MFMA count unchanged.
//  * A-side ds_read_b128 8 -> 16 per wave/group (256B/wave, LDS BW-cheap;
//    per t-step all 8 reads share one base VGPR + f*4096 immediate offsets).
//  * k-half pairs (w, w^4) merge accs via the same 32KB LDS exchange.
// Unchanged: exact-cancellation f16 magic dequant, XOR-swizzled async
// global_load_lds A-dbuf, split-K x4 grid (172,4), packed {s,-z1} szp table.

#define M_DIM 128
#define K_DIM 4096
#define N_DIM 11008
#define GS    128
#define NG    32
#define SPLIT 4
#define GPB   (NG / SPLIT)           // 8 groups per block
#define NB    (N_DIM / 64)           // 172 n-blocks
#define PART_ELEMS ((size_t)NB * 4 * 2048)   // halfs per split = 1,409,024

typedef _Float16 half8  __attribute__((ext_vector_type(8)));
typedef _Float16 half2t __attribute__((ext_vector_type(2)));
typedef _Float16 half4t __attribute__((ext_vector_type(4)));
typedef float    f32x4  __attribute__((ext_vector_type(4)));

// ---------------- prep ------------------------------------------------------
// blocks [0,512):    x f32 -> xh f16                 (512*256*4 == 524288)
// blocks [512,1888): szp packed {s, -(z+1)s} f16x2   (32 g x 43 nb x 256)
__global__ void k_prep(const float* __restrict__ x, const int* __restrict__ qzeros,
                       const float* __restrict__ scales,
                       _Float16* __restrict__ xh, _Float16* __restrict__ szp) {
    int b = blockIdx.x, tid = threadIdx.x;
    if (b < 512) {
        int i = (b * 256 + tid) * 4;
        float4 v = *(const float4*)(x + i);
        half4t o;
        o[0] = (_Float16)v.x; o[1] = (_Float16)v.y;
        o[2] = (_Float16)v.z; o[3] = (_Float16)v.w;
        *(half4t*)(xh + i) = o;
    } else {
        b -= 512;
        int g = b / 43;
        int n = (b - g * 43) * 256 + tid;            // 43*256 == 11008 exact
        unsigned qz = (unsigned)qzeros[g * (N_DIM / 8) + (n >> 3)];
        float s  = scales[g * N_DIM + n];
        float z1 = (float)((qz >> ((n & 7) * 4)) & 15u) + 1.0f;
        half2t o;
        o[0] = (_Float16)s;
        o[1] = (_Float16)(-(z1 * s));
        *(half2t*)(szp + (size_t)(g * N_DIM + n) * 2) = o;
    }
}

// async 16B/lane global->LDS; lds base wave-uniform, lane i -> base + i*16.
__device__ __forceinline__ void load_lds16(const void* g, void* l) {
    __builtin_amdgcn_global_load_lds(
        (const __attribute__((address_space(1))) unsigned int*)g,
        (__attribute__((address_space(3))) unsigned int*)l, 16, 0, 0);
}

// nibble pair p (nibbles 2p, 2p+1) of q -> two f16 weights:
//  t  = {0x6400|nib_lo, 0x6400|nib_hi<<4} = {1024+q_lo, 1024+16*q_hi}
//  qf = t - 1024                  (EXACT in f16: integers <= 2048)
//  w  = fma(qf, {s, s/16}, {-z1}) where z1 = (z+1)*s
// No pointer casts: pure vector ops, SROA-safe (scratch regression guard).
__device__ __forceinline__ half8 dequant8(unsigned q, half2t S2, half2t Z2) {
    const half2t BIAS = __builtin_bit_cast(half2t, 0x64006400u);
    half2t w[4];
#pragma unroll
    for (int p = 0; p < 4; ++p) {
        unsigned r = __builtin_amdgcn_perm(q, q, 0x00010001u * (unsigned)p); // byte p -> bytes 0,2
        unsigned t = (r & 0x00F0000Fu) | 0x64006400u;                        // v_and_or_b32
        w[p] = __builtin_elementwise_fma(__builtin_bit_cast(half2t, t) - BIAS, S2, Z2);
    }
    half4t lo = __builtin_shufflevector(w[0], w[1], 0, 1, 2, 3);
    half4t hi = __builtin_shufflevector(w[2], w[3], 0, 1, 2, 3);
    return __builtin_shufflevector(lo, hi, 0, 1, 2, 3, 4, 5, 6, 7);
}

// ---------------- main fused kernel ----------------
__global__ __launch_bounds__(512, 4)
void k_gemm(const _Float16* __restrict__ xh,     // [128][4096] f16
            const int*      __restrict__ qweight,// [512][11008] int32
            const _Float16* __restrict__ szp,    // [32][11008] packed {s,-z1}
            _Float16*       __restrict__ part)   // [SPLIT][flat] f16 partials
{
    // Double-buffered A tile: logical (m,kb) of buffer b at
    //   As[b][m*128 + (kb ^ (m&15))*8]   (halfs)
    // Staged so chunk c = it*512+tid lands at byte offset c*16.
    __shared__ _Float16 As[2][128 * 128];   // 2 x 32 KB

    const int tid  = threadIdx.x;
    const int lane = tid & 63;
    const int w    = tid >> 6;    // 0..7
    const int ns   = w & 3;        // n-slice: cols ns*16 .. ns*16+15
    const int kh   = w >> 2;       // k-half: kh=0 -> kk{0,1}, kh=1 -> kk{2,3}
    const int q    = lane >> 4;    // quad
    const int lr   = lane & 15;

    const int n0 = blockIdx.x * 64;
    const int g0 = blockIdx.y * GPB;
    const int ncol = n0 + ns * 16 + lr;

    f32x4 acc[8];
#pragma unroll
    for (int f = 0; f < 8; ++f)
        acc[f] = (f32x4){0.f, 0.f, 0.f, 0.f};

    // per-lane staging geometry: c = it*512 + tid; m=c>>4; kb=(c&15)^(m&15)
    int cm[4], ckb[4];
#pragma unroll
    for (int it = 0; it < 4; ++it) {
        int c = it * 512 + tid;
        cm[it]  = c >> 4;
        ckb[it] = (c & 15) ^ (cm[it] & 15);
    }
    const int wave_lds = w * 64 * 8;   // halfs

    // ---- prime group g0 ----
#pragma unroll
    for (int it = 0; it < 4; ++it)
        load_lds16(xh + (size_t)cm[it] * K_DIM + g0 * GS + ckb[it] * 8,
                   &As[0][it * 512 * 8 + wave_lds]);
    unsigned qwn[2];
    half2t   szn;
#pragma unroll
    for (int t = 0; t < 2; ++t)
        qwn[t] = (unsigned)qweight[(size_t)(g0 * 16 + (kh * 2 + t) * 4 + q) * N_DIM + ncol];
    szn = *(const half2t*)(szp + ((size_t)g0 * N_DIM + ncol) * 2);

    int p = 0;
    for (int g = 0; g < GPB; ++g) {
        unsigned qw[2];
        half2t   sz;
#pragma unroll
        for (int i = 0; i < 2; ++i) qw[i] = qwn[i];
        sz = szn;

        __syncthreads();   // A(g) resident in As[p]

        if (g + 1 < GPB) { // next group's async loads in flight under compute
            int gn = g0 + g + 1;
#pragma unroll
            for (int it = 0; it < 4; ++it)
                load_lds16(xh + (size_t)cm[it] * K_DIM + gn * GS + ckb[it] * 8,
                           &As[p ^ 1][it * 512 * 8 + wave_lds]);
#pragma unroll
            for (int t = 0; t < 2; ++t)
                qwn[t] = (unsigned)qweight[(size_t)(gn * 16 + (kh * 2 + t) * 4 + q) * N_DIM + ncol];
            szn = *(const half2t*)(szp + ((size_t)gn * N_DIM + ncol) * 2);
        }

        half2t S2, Z2;
        S2[0] = sz[0];
        S2[1] = sz[0] * (_Float16)0.0625f;   // exact pow2 scale
        Z2[0] = sz[1];
        Z2[1] = sz[1];

#pragma unroll
        for (int t = 0; t < 2; ++t) {
            const int kk = kh * 2 + t;
            half8 bf = dequant8(qw[t], S2, Z2);
            const int kb2 = (kk * 4 + q) ^ lr;   // m&15 == lr for all f below
#pragma unroll
            for (int f = 0; f < 8; ++f) {
                int m = f * 16 + lr;
                half8 af = *(const half8*)(&As[p][m * 128 + kb2 * 8]);
                acc[f] = __builtin_amdgcn_mfma_f32_16x16x32_f16(af, bf, acc[f], 0, 0, 0);
            }
        }
        p ^= 1;
    }

    // ---- pair reduction (w, w^4) through LDS, then store f16 partials ----
    __syncthreads();                       // all A reads done; LDS reusable
    float* red = (float*)&As[0][0];        // 32 KB: 4 pairs x 8 KB
    if (kh == 1) {
#pragma unroll
        for (int f = 0; f < 8; ++f)
            *(f32x4*)(red + ns * 2048 + f * 256 + lane * 4) = acc[f];
    }
    __syncthreads();
    if (kh == 0) {
        // flat layout: part[s][nb][ns][f][lane] as half4 -> 8B coalesced
        _Float16* ph = part + (size_t)blockIdx.y * PART_ELEMS
                     + (size_t)(blockIdx.x * 4 + ns) * 2048;
#pragma unroll
        for (int f = 0; f < 8; ++f) {
            f32x4 o = acc[f] + *(const f32x4*)(red + ns * 2048 + f * 256 + lane * 4);
            half4t ov;
#pragma unroll
            for (int r = 0; r < 4; ++r) ov[r] = (_Float16)o[r];
            *(half4t*)(ph + (f * 64 + lane) * 4) = ov;
        }
    }
}

// ---------------- reduce: out = bias + sum_s part[s] (decode flat layout) ---
__global__ void k_reduce(const _Float16* __restrict__ part, const float* __restrict__ bias,
                         float* __restrict__ out) {
    int t = blockIdx.x * 256 + threadIdx.x;   // 1376*256 = 352,256 = PART_ELEMS/4
    int lane = t & 63, f = (t >> 6) & 7, ns = (t >> 9) & 3, nb = t >> 11;
    int q = lane >> 4, lr = lane & 15;
    int m0 = f * 16 + q * 4;
    int n  = nb * 64 + ns * 16 + lr;
    f32x4 sv = (f32x4){0.f, 0.f, 0.f, 0.f};
#pragma unroll
    for (int s = 0; s < SPLIT; ++s) {
        half4t v = *(const half4t*)(part + s * PART_ELEMS + (size_t)t * 4);
#pragma unroll
        for (int r = 0; r < 4; ++r) sv[r] += (float)v[r];
    }
    float b = bias[n];
#pragma unroll
    for (int r = 0; r < 4; ++r)
        out[(size_t)(m0 + r) * N_DIM + n] = sv[r] + b;
}

extern "C" void kernel_launch(void* const* d_in, const int* in_sizes, int n_in,
                              void* d_out, int out_size, void* d_ws, size_t ws_size,
                              hipStream_t stream) {
    const float* x       = (const float*)d_in[0];
    const int*   qweight = (const int*)d_in[1];
    const int*   qzeros  = (const int*)d_in[2];
    const float* scales  = (const float*)d_in[3];
    const float* bias    = (const float*)d_in[4];
    // d_in[5] = g_idx, affine by construction -> unused

    char* ws = (char*)d_ws;
    _Float16* xh   = (_Float16*)ws;                          // 1,048,576 B
    _Float16* szp  = (_Float16*)(ws + 1048576);              // 1,409,024 B
    _Float16* part = (_Float16*)(ws + 1048576 + 1409024);    // 4 x 2,818,048 B

    k_prep  <<<dim3(1888),         dim3(256), 0, stream>>>(x, qzeros, scales, xh, szp);
    k_gemm  <<<dim3(NB, SPLIT),    dim3(512), 0, stream>>>(xh, qweight, szp, part);
    k_reduce<<<dim3(1376),         dim3(256), 0, stream>>>(part, bias, (float*)d_out);
}